// Round 2
// baseline (972.690 us; speedup 1.0000x reference)
//
#include <hip/hip_runtime.h>
#include <hip/hip_bf16.h>

#define N 3072
#define D 128
#define NAA 20
#define NH 8
#define HID 256
#define STRIDE 164  // 32 rows of 160 f32, padded to 164 (float4-aligned)

__device__ __forceinline__ float gelu_tanh(float v) {
    float u = 0.7978845608028654f * (v + 0.044715f * v * v * v);
    return 0.5f * v * (1.0f + tanhf(u));
}

// Kernel A: per-row MLP -> features -> dcode[i,a,x], gmix[j,a,x]=sum_b gelu(dgate)[j,b,x]*w[a,b,x]
// Stored layout: row*160 + x*8 + a   (a contiguous => kernel B reads 2x float4 per (row,x))
__global__ __launch_bounds__(256) void row_kernel(
    const float* __restrict__ local, const int* __restrict__ aa,
    const float* __restrict__ W1, const float* __restrict__ W2,
    const float* __restrict__ Wc, const float* __restrict__ Wg,
    const float* __restrict__ iw,
    float* __restrict__ dcode_o, float* __restrict__ gmix_o)
{
    __shared__ float xs[D];
    __shared__ float hs[HID];
    __shared__ float fs[D];
    __shared__ float dg[NH * NAA];
    const int row = blockIdx.x;
    const int tid = threadIdx.x;

    if (tid < D) xs[tid] = local[row * D + tid];
    const int a_idx = aa[row];
    __syncthreads();

    // h = gelu(x @ W1); one-hot handled as adding W1 row (128 + aa)
    {
        float acc = W1[(D + a_idx) * HID + tid];
        for (int k = 0; k < D; ++k) acc += xs[k] * W1[k * HID + tid];
        hs[tid] = gelu_tanh(acc);
    }
    __syncthreads();

    // features = h @ W2
    if (tid < D) {
        float acc = 0.f;
        for (int k = 0; k < HID; ++k) acc += hs[k] * W2[k * D + tid];
        fs[tid] = acc;
    }
    __syncthreads();

    // dcode = features @ Wc  (col c = a*20 + x), store a-contiguous
    if (tid < NH * NAA) {
        float acc = 0.f;
        for (int k = 0; k < D; ++k) acc += fs[k] * Wc[k * NH * NAA + tid];
        int hh = tid / NAA, x = tid % NAA;
        dcode_o[(size_t)row * 160 + x * NH + hh] = acc;
    }
    // dgate = gelu(features @ Wg)  (threads 96..255 cover the 160 cols)
    if (tid >= 96) {
        int t2 = tid - 96;
        float acc = 0.f;
        for (int k = 0; k < D; ++k) acc += fs[k] * Wg[k * NH * NAA + t2];
        dg[t2] = gelu_tanh(acc);  // dg[b*20 + x]
    }
    __syncthreads();

    // gmix[a,x] = sum_b dg[b,x] * iw[a,b,x];  tid = x*8 + a
    if (tid < NH * NAA) {
        int x = tid >> 3, a = tid & 7;
        float acc = 0.f;
        for (int b = 0; b < NH; ++b)
            acc += dg[b * NAA + x] * iw[(a * NH + b) * NAA + x];
        gmix_o[(size_t)row * 160 + tid] = acc;
    }
}

// Kernel B: 32x32 pair tile per block, 2x2 pairs per thread, full softmax in-lane.
__global__ __launch_bounds__(256) void pair_kernel(
    const float* __restrict__ dcode_l, const float* __restrict__ gmix_l,
    float* __restrict__ out)
{
    __shared__ float ds[32 * STRIDE];
    __shared__ float gs[32 * STRIDE];
    const int tid = threadIdx.x;
    const int i0 = blockIdx.y * 32, j0 = blockIdx.x * 32;

    // stage 32 rows x 160 f32 of each table (40 float4 per row)
    for (int v = tid; v < 32 * 40; v += 256) {
        int r = v / 40, c = v % 40;
        ((float4*)&ds[r * STRIDE])[c] = ((const float4*)&dcode_l[(size_t)(i0 + r) * 160])[c];
        ((float4*)&gs[r * STRIDE])[c] = ((const float4*)&gmix_l[(size_t)(j0 + r) * 160])[c];
    }
    __syncthreads();

    // 8x8 lane grid per wave, 2x2 wave grid per block -> 16x16 (i-pair, j-pair) grid
    const int lane = tid & 63, wid = tid >> 6;
    const int ti2 = ((wid >> 1) << 3) + (lane >> 3);  // 0..15
    const int tj2 = ((wid & 1) << 3) + (lane & 7);    // 0..15

    const float* dp0 = &ds[(ti2 * 2    ) * STRIDE];
    const float* dp1 = &ds[(ti2 * 2 + 1) * STRIDE];
    const float* gp0 = &gs[(tj2 * 2    ) * STRIDE];
    const float* gp1 = &gs[(tj2 * 2 + 1) * STRIDE];

    float acc[2][2][NAA];
#pragma unroll
    for (int x = 0; x < NAA; ++x) {
        float4 a0 = *(const float4*)&dp0[x * 8];
        float4 a1 = *(const float4*)&dp0[x * 8 + 4];
        float4 b0 = *(const float4*)&dp1[x * 8];
        float4 b1 = *(const float4*)&dp1[x * 8 + 4];
        float4 c0 = *(const float4*)&gp0[x * 8];
        float4 c1 = *(const float4*)&gp0[x * 8 + 4];
        float4 e0 = *(const float4*)&gp1[x * 8];
        float4 e1 = *(const float4*)&gp1[x * 8 + 4];
        acc[0][0][x] = a0.x*c0.x + a0.y*c0.y + a0.z*c0.z + a0.w*c0.w
                     + a1.x*c1.x + a1.y*c1.y + a1.z*c1.z + a1.w*c1.w;
        acc[0][1][x] = a0.x*e0.x + a0.y*e0.y + a0.z*e0.z + a0.w*e0.w
                     + a1.x*e1.x + a1.y*e1.y + a1.z*e1.z + a1.w*e1.w;
        acc[1][0][x] = b0.x*c0.x + b0.y*c0.y + b0.z*c0.z + b0.w*c0.w
                     + b1.x*c1.x + b1.y*c1.y + b1.z*c1.z + b1.w*c1.w;
        acc[1][1][x] = b0.x*e0.x + b0.y*e0.y + b0.z*e0.z + b0.w*e0.w
                     + b1.x*e1.x + b1.y*e1.y + b1.z*e1.z + b1.w*e1.w;
    }

#pragma unroll
    for (int pi = 0; pi < 2; ++pi) {
#pragma unroll
        for (int pj = 0; pj < 2; ++pj) {
            float* l = acc[pi][pj];
            float m = l[0];
#pragma unroll
            for (int x = 1; x < NAA; ++x) m = fmaxf(m, l[x]);
            float s = 0.f;
#pragma unroll
            for (int x = 0; x < NAA; ++x) s += __expf(l[x] - m);
            float c = m + __logf(s);
            size_t i = (size_t)(i0 + ti2 * 2 + pi);
            size_t j = (size_t)(j0 + tj2 * 2 + pj);
            float* dst = out + (i * (size_t)N + j) * NAA;
            float4 o0 = make_float4(l[0] - c, l[1] - c, l[2] - c, l[3] - c);
            float4 o1 = make_float4(l[4] - c, l[5] - c, l[6] - c, l[7] - c);
            float4 o2 = make_float4(l[8] - c, l[9] - c, l[10] - c, l[11] - c);
            float4 o3 = make_float4(l[12] - c, l[13] - c, l[14] - c, l[15] - c);
            float4 o4 = make_float4(l[16] - c, l[17] - c, l[18] - c, l[19] - c);
            ((float4*)dst)[0] = o0;
            ((float4*)dst)[1] = o1;
            ((float4*)dst)[2] = o2;
            ((float4*)dst)[3] = o3;
            ((float4*)dst)[4] = o4;
        }
    }
}

extern "C" void kernel_launch(void* const* d_in, const int* in_sizes, int n_in,
                              void* d_out, int out_size, void* d_ws, size_t ws_size,
                              hipStream_t stream) {
    const float* local = (const float*)d_in[0];
    const int*   aa    = (const int*)d_in[1];
    const float* W1    = (const float*)d_in[2];
    const float* W2    = (const float*)d_in[3];
    const float* Wc    = (const float*)d_in[4];
    const float* Wg    = (const float*)d_in[5];
    const float* iw    = (const float*)d_in[6];

    float* dcode_l = (float*)d_ws;
    float* gmix_l  = dcode_l + (size_t)N * 160;
    float* out     = (float*)d_out;

    hipLaunchKernelGGL(row_kernel, dim3(N), dim3(256), 0, stream,
                       local, aa, W1, W2, Wc, Wg, iw, dcode_l, gmix_l);
    hipLaunchKernelGGL(pair_kernel, dim3(N / 32, N / 32), dim3(256), 0, stream,
                       dcode_l, gmix_l, out);
}